// Round 12
// baseline (252.401 us; speedup 1.0000x reference)
//
#include <hip/hip_runtime.h>
#include <hip/hip_bf16.h>
#include <math.h>

// GAT encoder, round 21.  5 dispatches:
//  prep_all (x->Xhi, W1hi, W2hi, zero cnt) | gemm1+fill (128x128 tile, 1D
//  grid rblk/head, fill grid-strided 512 blocks) | agg1 | gemm2 | agg2.
// Round-20 post-mortem: gemm1+fill was 58us @ occupancy 9% -- the r17
// head-merge (acc[4][8] = 192 VGPR, 32KB LDS -> 2 blocks/CU) was a hidden
// regression, and 2344 trailing fill blocks each hogged the full footprint
// (4.6 scheduling rounds).  Bank conflicts (1.2M ~ 2us) were a red herring.
// Round-21: revert to r14's 128x128 tile (acc[4][4], ~130 VGPR, 22.5KB LDS
// -> ~4 blocks/CU), flatten grid (rblk=bx>>1, head=bx&1 for Xhi L2 reuse),
// fill grid-strided over 512 blocks.  h1b bits identical; al1s epilogue =
// r14's proven two-half sum.  absmax 0.00390625 expected unchanged.

#define NSLOPE 0.2f

using bf16x8 = __attribute__((ext_vector_type(8))) short;
using f32x4  = __attribute__((ext_vector_type(4))) float;
using u16x8  = __attribute__((ext_vector_type(8))) unsigned short;
using u16x4  = __attribute__((ext_vector_type(4))) unsigned short;

__device__ __forceinline__ unsigned short bf16_rne(float f) {
    unsigned u = __float_as_uint(f);
    return (unsigned short)((u + 0x7FFFu + ((u >> 16) & 1u)) >> 16);
}
__device__ __forceinline__ float bf16_to_f(unsigned short h) {
    return __uint_as_float(((unsigned)h) << 16);
}

// ----- merged prep: x->Xhi | W1->W1hi (transposed) | W2->W2hi | zero cnt ----
__global__ __launch_bounds__(256) void k_prep_all(const float* __restrict__ x,
                                                  const float* __restrict__ W1,
                                                  const float* __restrict__ W2,
                                                  unsigned short* __restrict__ Xhi,
                                                  unsigned short* __restrict__ W1hi,
                                                  unsigned short* __restrict__ W2hi,
                                                  int* __restrict__ cnt,
                                                  int BX, int total4, int N) {
    int b = blockIdx.x, t = threadIdx.x;
    if (b < BX) {  // x -> bf16 (hi only): 4 floats / thread
        int id = b * 256 + t;
        if (id >= total4) return;
        float4 v = *(const float4*)&x[(size_t)id * 4];
        unsigned short hi[4];
        hi[0] = bf16_rne(v.x); hi[1] = bf16_rne(v.y);
        hi[2] = bf16_rne(v.z); hi[3] = bf16_rne(v.w);
        *(u16x4*)&Xhi[(size_t)id * 4] = *(u16x4*)hi;
    } else if (b < BX + 64) {  // transpose W1 [256,256] -> [n][k], bf16
        int id = (b - BX) * 256 + t;
        int n = id >> 6, kg = id & 63;
        unsigned short hi[4];
#pragma unroll
        for (int c = 0; c < 4; ++c) {
            float w = W1[(kg * 4 + c) * 256 + n];
            hi[c] = bf16_rne(w);
        }
        *(u16x4*)&W1hi[n * 256 + kg * 4] = *(u16x4*)hi;
    } else if (b < BX + 128) {  // transpose W2 [256,64] -> [n][k], bf16
        int id = (b - BX - 64) * 256 + t;
        int n = id >> 8, k = id & 255;
        W2hi[n * 256 + k] = bf16_rne(W2[k * 64 + n]);
    } else {  // zero cnt
        int i = (b - BX - 128) * 256 + t;
        if (i < N) cnt[i] = 0;
    }
}

// -- GEMM1 (+fused fill): 128x128 tile, 1D grid (rblk, head); alpha1 fused ---
#define G1S 40  // LDS row stride in ushort (32 k + 8 pad)
__global__ __launch_bounds__(256) void k_gemm1(const unsigned short* __restrict__ Xhi,
                                               const unsigned short* __restrict__ Whi,
                                               const float* __restrict__ a1s,
                                               const float* __restrict__ a1d,
                                               unsigned short* __restrict__ h1b,
                                               float* __restrict__ as_,
                                               float* __restrict__ ad_, int M,
                                               const int* __restrict__ esrc,
                                               const int* __restrict__ edst,
                                               int* __restrict__ cnt,
                                               int* __restrict__ bucket,
                                               int E, int NG, int FBL) {
    __shared__ unsigned short sAh[128 * G1S];
    __shared__ unsigned short sBh[128 * G1S];
    __shared__ float salS[128][2], salD[128][2];
    int t = threadIdx.x;
    if (blockIdx.x >= NG) {  // trailing blocks: bucket fill, grid-strided
        int nthr = FBL * 256;
        for (int i = (blockIdx.x - NG) * 256 + t; i < E; i += nthr) {
            int s = esrc[i], d = edst[i];
            int p = atomicAdd(&cnt[d], 1);
            if (p < 63) bucket[(size_t)d * 64 + p] = s;
        }
        return;
    }
    int lane = t & 63, wave = t >> 6;
    int q = lane >> 4, m = lane & 15;
    int row0 = (blockIdx.x >> 1) * 128;
    int head = blockIdx.x & 1;
    int col0 = head * 128;
    int rbase = (wave & 1) * 64, cbase = (wave >> 1) * 64;
    f32x4 acc[4][4];
#pragma unroll
    for (int i = 0; i < 4; ++i)
#pragma unroll
        for (int j = 0; j < 4; ++j) acc[i][j] = (f32x4){0.f, 0.f, 0.f, 0.f};

    for (int kc = 0; kc < 256; kc += 32) {
        // stage A: 128 rows x 32 k, 512 u16x8 slots
#pragma unroll
        for (int i2 = 0; i2 < 2; ++i2) {
            int slot = t + i2 * 256;
            int r = slot >> 2, kg = slot & 3;
            int row = row0 + r;
            u16x8 vh = {0, 0, 0, 0, 0, 0, 0, 0};
            if (row < M) vh = *(const u16x8*)&Xhi[(size_t)row * 256 + kc + kg * 8];
            *(u16x8*)&sAh[r * G1S + kg * 8] = vh;
        }
        // stage B: 128 cols x 32 k, pre-transposed W [n][k]
#pragma unroll
        for (int i2 = 0; i2 < 2; ++i2) {
            int slot = t + i2 * 256;
            int n = slot >> 2, kg = slot & 3;
            *(u16x8*)&sBh[n * G1S + kg * 8] =
                *(const u16x8*)&Whi[(size_t)(col0 + n) * 256 + kc + kg * 8];
        }
        __syncthreads();
        bf16x8 ah[4], bh[4];
#pragma unroll
        for (int i = 0; i < 4; ++i)
            ah[i] = *(bf16x8*)&sAh[(rbase + i * 16 + m) * G1S + q * 8];
#pragma unroll
        for (int j = 0; j < 4; ++j)
            bh[j] = *(bf16x8*)&sBh[(cbase + j * 16 + m) * G1S + q * 8];
#pragma unroll
        for (int i = 0; i < 4; ++i)
#pragma unroll
            for (int j = 0; j < 4; ++j)
                acc[i][j] = __builtin_amdgcn_mfma_f32_16x16x32_bf16(ah[i], bh[j], acc[i][j], 0, 0, 0);
        __syncthreads();
    }
    float sv[4], dv[4];
#pragma unroll
    for (int j = 0; j < 4; ++j) {
        sv[j] = a1s[head * 128 + cbase + j * 16 + m];
        dv[j] = a1d[head * 128 + cbase + j * 16 + m];
    }
#pragma unroll
    for (int i = 0; i < 4; ++i) {
#pragma unroll
        for (int r = 0; r < 4; ++r) {
            int rl = rbase + i * 16 + q * 4 + r;
            int row = row0 + rl;
            float ps = acc[i][0][r] * sv[0] + acc[i][1][r] * sv[1]
                     + acc[i][2][r] * sv[2] + acc[i][3][r] * sv[3];
            float pd = acc[i][0][r] * dv[0] + acc[i][1][r] * dv[1]
                     + acc[i][2][r] * dv[2] + acc[i][3][r] * dv[3];
#pragma unroll
            for (int mask = 1; mask < 16; mask <<= 1) {
                ps += __shfl_xor(ps, mask, 64);
                pd += __shfl_xor(pd, mask, 64);
            }
            if (m == 0) {
                salS[rl][cbase >> 6] = ps;
                salD[rl][cbase >> 6] = pd;
            }
            if (row < M) {
#pragma unroll
                for (int j = 0; j < 4; ++j)
                    h1b[(size_t)row * 256 + col0 + cbase + j * 16 + m] = bf16_rne(acc[i][j][r]);
            }
        }
    }
    __syncthreads();
    if (t < 128) {
        int row = row0 + t;
        if (row < M) {
            as_[row * 2 + head] = salS[t][0] + salS[t][1];
            ad_[row * 2 + head] = salD[t][0] + salD[t][1];
        }
    }
}

// ------- layer-1 aggregate: bucket-based, half-wave/edge, 4/2/1 ladder ------
__global__ __launch_bounds__(256) void k_agg1(const unsigned short* __restrict__ h1b,
                                              const float* __restrict__ as,
                                              const float* __restrict__ ad,
                                              const int* __restrict__ cnt,
                                              const int* __restrict__ bucket,
                                              const float* __restrict__ b1,
                                              unsigned short* __restrict__ helu_b, int N) {
    int wid = (blockIdx.x * blockDim.x + threadIdx.x) >> 6;
    int lane = threadIdx.x & 63;
    if (wid >= N) return;
    int c = min(cnt[wid], 63);
    int cntTot = c + 1;   // + self-loop at lane c
    float ad0 = ad[wid * 2], ad1 = ad[wid * 2 + 1];
    int half = lane >> 5, hl = lane & 31;
    int headL = hl >> 4;
    float acc[8];
#pragma unroll
    for (int cc = 0; cc < 8; ++cc) acc[cc] = 0.f;
    float sumw = 0.f;

    int s = (lane < c) ? bucket[(size_t)wid * 64 + lane] : wid;
    float w0 = 0.f, w1 = 0.f;
    if (lane <= c) {
        float2 av = *(const float2*)&as[s * 2];
        float l0 = av.x + ad0; l0 = l0 >= 0.f ? l0 : NSLOPE * l0;
        float l1 = av.y + ad1; l1 = l1 >= 0.f ? l1 : NSLOPE * l1;
        w0 = __expf(l0); w1 = __expf(l1);
    }
    int pairs = (cntTot + 1) >> 1;
    int jj = 0;
    for (; jj + 4 <= pairs; jj += 4) {
        int e0 = 2 * jj + half, e1 = e0 + 2, e2 = e0 + 4, e3 = e0 + 6;
        int sa = __shfl(s, e0, 64), sb = __shfl(s, e1, 64);
        int sc = __shfl(s, e2, 64), se = __shfl(s, e3, 64);
        float wa0 = __shfl(w0, e0, 64), wa1 = __shfl(w1, e0, 64);
        float wb0 = __shfl(w0, e1, 64), wb1 = __shfl(w1, e1, 64);
        float wc0 = __shfl(w0, e2, 64), wc1 = __shfl(w1, e2, 64);
        float wd0 = __shfl(w0, e3, 64), wd1 = __shfl(w1, e3, 64);
        u16x8 hva = *(const u16x8*)&h1b[(size_t)sa * 256 + hl * 8];
        u16x8 hvb = *(const u16x8*)&h1b[(size_t)sb * 256 + hl * 8];
        u16x8 hvc = *(const u16x8*)&h1b[(size_t)sc * 256 + hl * 8];
        u16x8 hvd = *(const u16x8*)&h1b[(size_t)se * 256 + hl * 8];
        float wa = headL ? wa1 : wa0;
        float wb = headL ? wb1 : wb0;
        float wc = headL ? wc1 : wc0;
        float wd = headL ? wd1 : wd0;
        sumw += (wa + wb) + (wc + wd);
#pragma unroll
        for (int cc = 0; cc < 8; ++cc)
            acc[cc] += (wa * bf16_to_f(hva[cc]) + wb * bf16_to_f(hvb[cc]))
                     + (wc * bf16_to_f(hvc[cc]) + wd * bf16_to_f(hvd[cc]));
    }
    for (; jj + 2 <= pairs; jj += 2) {
        int e0 = 2 * jj + half, e1 = e0 + 2;
        int sa = __shfl(s, e0, 64), sb = __shfl(s, e1, 64);
        float wa0 = __shfl(w0, e0, 64), wa1 = __shfl(w1, e0, 64);
        float wb0 = __shfl(w0, e1, 64), wb1 = __shfl(w1, e1, 64);
        u16x8 hva = *(const u16x8*)&h1b[(size_t)sa * 256 + hl * 8];
        u16x8 hvb = *(const u16x8*)&h1b[(size_t)sb * 256 + hl * 8];
        float wa = headL ? wa1 : wa0;
        float wb = headL ? wb1 : wb0;
        sumw += wa + wb;
#pragma unroll
        for (int cc = 0; cc < 8; ++cc)
            acc[cc] += wa * bf16_to_f(hva[cc]) + wb * bf16_to_f(hvb[cc]);
    }
    for (; jj < pairs; ++jj) {
        int e0 = 2 * jj + half;
        int sa = __shfl(s, e0, 64);
        float wa0 = __shfl(w0, e0, 64), wa1 = __shfl(w1, e0, 64);
        u16x8 hva = *(const u16x8*)&h1b[(size_t)sa * 256 + hl * 8];
        float wa = headL ? wa1 : wa0;
        sumw += wa;
#pragma unroll
        for (int cc = 0; cc < 8; ++cc) acc[cc] += wa * bf16_to_f(hva[cc]);
    }
#pragma unroll
    for (int cc = 0; cc < 8; ++cc) acc[cc] += __shfl_xor(acc[cc], 32, 64);
    sumw += __shfl_xor(sumw, 32, 64);
    float inv = 1.0f / sumw;
    int ch = hl * 8 + half * 4;
    float4 bv = *(const float4*)&b1[ch];
    float bb[4] = {bv.x, bv.y, bv.z, bv.w};
    unsigned short o[4];
#pragma unroll
    for (int cc = 0; cc < 4; ++cc) {
        float v = acc[half * 4 + cc] * inv + bb[cc];
        v = v > 0.f ? v : expm1f(v);
        o[cc] = bf16_rne(v);
    }
    *(u16x4*)&helu_b[(size_t)wid * 256 + ch] = *(u16x4*)o;
}

// ---------------- GEMM2: 1-term bf16-A x bf16-B MFMA, alpha2 fused ----------
__global__ __launch_bounds__(256) void k_gemm2(const unsigned short* __restrict__ hb,
                                               const unsigned short* __restrict__ Whi,
                                               const float* __restrict__ a2s,
                                               const float* __restrict__ a2d,
                                               unsigned short* __restrict__ h2b,
                                               float* __restrict__ as_,
                                               float* __restrict__ ad_, int M) {
    __shared__ unsigned short sA[128 * G1S];
    __shared__ unsigned short sBh[64 * G1S];
    int t = threadIdx.x;
    int lane = t & 63, wave = t >> 6;
    int q = lane >> 4, m = lane & 15;
    int row0 = blockIdx.x * 128;
    int rbase = wave * 32;
    f32x4 acc[2][4];
#pragma unroll
    for (int i = 0; i < 2; ++i)
#pragma unroll
        for (int j = 0; j < 4; ++j) acc[i][j] = (f32x4){0.f, 0.f, 0.f, 0.f};

    for (int kc = 0; kc < 256; kc += 32) {
#pragma unroll
        for (int i = 0; i < 2; ++i) {
            int slot = t + i * 256;
            int r = slot >> 2, kg = slot & 3;
            int row = row0 + r;
            u16x8 v = {0, 0, 0, 0, 0, 0, 0, 0};
            if (row < M) v = *(const u16x8*)&hb[(size_t)row * 256 + kc + kg * 8];
            *(u16x8*)&sA[r * G1S + kg * 8] = v;
        }
        {
            int n = t >> 2, kg = t & 3;
            *(u16x8*)&sBh[n * G1S + kg * 8] =
                *(const u16x8*)&Whi[(size_t)n * 256 + kc + kg * 8];
        }
        __syncthreads();
        bf16x8 a[2], bh[4];
#pragma unroll
        for (int i = 0; i < 2; ++i)
            a[i] = *(bf16x8*)&sA[(rbase + i * 16 + m) * G1S + q * 8];
#pragma unroll
        for (int j = 0; j < 4; ++j)
            bh[j] = *(bf16x8*)&sBh[(j * 16 + m) * G1S + q * 8];
#pragma unroll
        for (int i = 0; i < 2; ++i)
#pragma unroll
            for (int j = 0; j < 4; ++j)
                acc[i][j] = __builtin_amdgcn_mfma_f32_16x16x32_bf16(a[i], bh[j], acc[i][j], 0, 0, 0);
        __syncthreads();
    }
    float sv[4], dv[4];
#pragma unroll
    for (int j = 0; j < 4; ++j) {
        sv[j] = a2s[j * 16 + m];
        dv[j] = a2d[j * 16 + m];
    }
#pragma unroll
    for (int i = 0; i < 2; ++i) {
#pragma unroll
        for (int r = 0; r < 4; ++r) {
            int row = row0 + rbase + i * 16 + q * 4 + r;
            float ps = acc[i][0][r] * sv[0] + acc[i][1][r] * sv[1]
                     + acc[i][2][r] * sv[2] + acc[i][3][r] * sv[3];
            float pd = acc[i][0][r] * dv[0] + acc[i][1][r] * dv[1]
                     + acc[i][2][r] * dv[2] + acc[i][3][r] * dv[3];
#pragma unroll
            for (int mask = 1; mask < 16; mask <<= 1) {
                ps += __shfl_xor(ps, mask, 64);
                pd += __shfl_xor(pd, mask, 64);
            }
            if (row < M) {
#pragma unroll
                for (int j = 0; j < 4; ++j)
                    h2b[(size_t)row * 64 + j * 16 + m] = bf16_rne(acc[i][j][r]);
                if (m == 0) { as_[row] = ps; ad_[row] = pd; }
            }
        }
    }
}

// ------- layer-2 aggregate: bucket-based, quarter-wave/edge, 4/2/1 ladder ---
__global__ __launch_bounds__(256) void k_agg2(const unsigned short* __restrict__ h2b,
                                              const float* __restrict__ as,
                                              const float* __restrict__ ad,
                                              const int* __restrict__ cnt,
                                              const int* __restrict__ bucket,
                                              const float* __restrict__ b2,
                                              float* __restrict__ out, int N) {
    int wid = (blockIdx.x * blockDim.x + threadIdx.x) >> 6;
    int lane = threadIdx.x & 63;
    if (wid >= N) return;
    int c = min(cnt[wid], 63);
    int cntTot = c + 1;
    float adw = ad[wid];
    int g = lane >> 4, gl = lane & 15;
    float acc[4];
#pragma unroll
    for (int cc = 0; cc < 4; ++cc) acc[cc] = 0.f;
    float sumw = 0.f;

    int s = (lane < c) ? bucket[(size_t)wid * 64 + lane] : wid;
    float w = 0.f;
    if (lane <= c) {
        float l = as[s] + adw;
        l = l >= 0.f ? l : NSLOPE * l;
        w = __expf(l);
    }
    int quads = (cntTot + 3) >> 2;
    int jj = 0;
    for (; jj + 4 <= quads; jj += 4) {
        int e0 = 4 * jj + g, e1 = e0 + 4, e2 = e0 + 8, e3 = e0 + 12;
        int sa = __shfl(s, e0, 64), sb = __shfl(s, e1, 64);
        int sc = __shfl(s, e2, 64), se = __shfl(s, e3, 64);
        float wa = __shfl(w, e0, 64), wb = __shfl(w, e1, 64);
        float wc = __shfl(w, e2, 64), wd = __shfl(w, e3, 64);
        u16x4 hva = *(const u16x4*)&h2b[(size_t)sa * 64 + gl * 4];
        u16x4 hvb = *(const u16x4*)&h2b[(size_t)sb * 64 + gl * 4];
        u16x4 hvc = *(const u16x4*)&h2b[(size_t)sc * 64 + gl * 4];
        u16x4 hvd = *(const u16x4*)&h2b[(size_t)se * 64 + gl * 4];
        sumw += (wa + wb) + (wc + wd);
        acc[0] += (wa * bf16_to_f(hva.x) + wb * bf16_to_f(hvb.x))
                + (wc * bf16_to_f(hvc.x) + wd * bf16_to_f(hvd.x));
        acc[1] += (wa * bf16_to_f(hva.y) + wb * bf16_to_f(hvb.y))
                + (wc * bf16_to_f(hvc.y) + wd * bf16_to_f(hvd.y));
        acc[2] += (wa * bf16_to_f(hva.z) + wb * bf16_to_f(hvb.z))
                + (wc * bf16_to_f(hvc.z) + wd * bf16_to_f(hvd.z));
        acc[3] += (wa * bf16_to_f(hva.w) + wb * bf16_to_f(hvb.w))
                + (wc * bf16_to_f(hvc.w) + wd * bf16_to_f(hvd.w));
    }
    for (; jj + 2 <= quads; jj += 2) {
        int e0 = 4 * jj + g, e1 = e0 + 4;
        int sa = __shfl(s, e0, 64), sb = __shfl(s, e1, 64);
        float wa = __shfl(w, e0, 64), wb = __shfl(w, e1, 64);
        u16x4 hva = *(const u16x4*)&h2b[(size_t)sa * 64 + gl * 4];
        u16x4 hvb = *(const u16x4*)&h2b[(size_t)sb * 64 + gl * 4];
        sumw += wa + wb;
        acc[0] += wa * bf16_to_f(hva.x) + wb * bf16_to_f(hvb.x);
        acc[1] += wa * bf16_to_f(hva.y) + wb * bf16_to_f(hvb.y);
        acc[2] += wa * bf16_to_f(hva.z) + wb * bf16_to_f(hvb.z);
        acc[3] += wa * bf16_to_f(hva.w) + wb * bf16_to_f(hvb.w);
    }
    for (; jj < quads; ++jj) {
        int e0 = 4 * jj + g;
        int sa = __shfl(s, e0, 64);
        float wa = __shfl(w, e0, 64);
        u16x4 hva = *(const u16x4*)&h2b[(size_t)sa * 64 + gl * 4];
        sumw += wa;
        acc[0] += wa * bf16_to_f(hva.x);
        acc[1] += wa * bf16_to_f(hva.y);
        acc[2] += wa * bf16_to_f(hva.z);
        acc[3] += wa * bf16_to_f(hva.w);
    }
#pragma unroll
    for (int cc = 0; cc < 4; ++cc) {
        acc[cc] += __shfl_xor(acc[cc], 16, 64);
        acc[cc] += __shfl_xor(acc[cc], 32, 64);
    }
    sumw += __shfl_xor(sumw, 16, 64);
    sumw += __shfl_xor(sumw, 32, 64);
    if (g == 0) {
        float inv = 1.0f / sumw;
        float4 bv = *(const float4*)&b2[gl * 4];
        float4 o;
        o.x = acc[0] * inv + bv.x;
        o.y = acc[1] * inv + bv.y;
        o.z = acc[2] * inv + bv.z;
        o.w = acc[3] * inv + bv.w;
        *(float4*)&out[(size_t)wid * 64 + gl * 4] = o;
    }
}

// ---------------- launch ----------------
extern "C" void kernel_launch(void* const* d_in, const int* in_sizes, int n_in,
                              void* d_out, int out_size, void* d_ws, size_t ws_size,
                              hipStream_t stream) {
    if (n_in < 10) return;
    const float* x   = (const float*)d_in[0];
    const int*   ei  = (const int*)d_in[1];
    const float* W1  = (const float*)d_in[2];
    const float* a1s = (const float*)d_in[3];
    const float* a1d = (const float*)d_in[4];
    const float* b1  = (const float*)d_in[5];
    const float* W2  = (const float*)d_in[6];
    const float* a2s = (const float*)d_in[7];
    const float* a2d = (const float*)d_in[8];
    const float* b2  = (const float*)d_in[9];
    float* out = (float*)d_out;

    const int N = in_sizes[0] / 256;
    const int E = in_sizes[1] / 2;
    const int* esrc = ei;
    const int* edst = ei + E;

    char* ws = (char*)d_ws;
    size_t o = 0;
    auto alloc = [&](size_t bytes) -> void* {
        void* p = ws + o;
        o = (o + bytes + 255) & ~(size_t)255;
        return p;
    };
    // Xhi (dead after gemm1) aliased with helu_b (written by agg1)
    size_t szX = (size_t)N * 256 * 2;
    char* regionA = (char*)alloc(szX);
    unsigned short* Xhi    = (unsigned short*)regionA;
    unsigned short* helu_b = (unsigned short*)regionA;

    unsigned short* h1b  = (unsigned short*)alloc((size_t)N * 256 * 2);
    unsigned short* W1hi = (unsigned short*)alloc(256 * 256 * 2);
    unsigned short* W2hi = (unsigned short*)alloc(64 * 256 * 2);
    unsigned short* h2b  = (unsigned short*)alloc((size_t)N * 64 * 2);
    float* al1s = (float*)alloc((size_t)N * 2 * 4);
    float* al1d = (float*)alloc((size_t)N * 2 * 4);
    float* al2s = (float*)alloc((size_t)N * 4);
    float* al2d = (float*)alloc((size_t)N * 4);
    int* cnt    = (int*)alloc((size_t)N * 4);
    int* bucket = (int*)alloc((size_t)N * 64 * 4);
    if (o > ws_size) return;

    const int total4 = N * 64;
    const int BX = (total4 + 255) / 256;
    const int BZ = (N + 255) / 256;
    const int NG = 2 * ((N + 127) / 128);  // gemm blocks (rblk x head)
    const int FBL = 512;                   // grid-strided fill blocks

    k_prep_all<<<BX + 128 + BZ, 256, 0, stream>>>(x, W1, W2, Xhi,
                                                  W1hi, W2hi, cnt,
                                                  BX, total4, N);
    k_gemm1<<<NG + FBL, 256, 0, stream>>>(Xhi, W1hi, a1s, a1d, h1b, al1s, al1d, N,
                                          esrc, edst, cnt, bucket, E, NG, FBL);
    k_agg1<<<(N + 3) / 4, 256, 0, stream>>>(h1b, al1s, al1d, cnt, bucket, b1, helu_b, N);

    // layer 2
    k_gemm2<<<(N + 127) / 128, 256, 0, stream>>>(helu_b, W2hi, a2s, a2d,
                                                 h2b, al2s, al2d, N);
    k_agg2<<<(N + 3) / 4, 256, 0, stream>>>(h2b, al2s, al2d, cnt, bucket, b2, out, N);
}

// Round 13
// 241.137 us; speedup vs baseline: 1.0467x; 1.0467x over previous
//
#include <hip/hip_runtime.h>
#include <hip/hip_bf16.h>
#include <math.h>

// GAT encoder, round 22.  5 dispatches:
//  prep_all (x->Xhi, W1hi, W2hi, zero cnt) | gemm1+fill (64x256 head-merged
//  tile, launch_bounds(256,4), one-shot trailing fill) | agg1 | gemm2 | agg2.
// Round-21 post-mortem: 128x128 split regressed (58->76us) despite occ 9->22%
// -- 2x A-staging (per-head) + grid-strided fill serialization; gemm1 is NOT
// occupancy-starved per se, it's barrier/latency-bound (MfmaUtil 3-4%, pure
// MFMA = 2.6us of ~50us).  Round-22: r20 base (241.2us) with gemm1 tile
// 64x256: A staged once per row (no per-head dup), 782 blocks, acc[16]=64
// VGPR + launch_bounds(256,4) pins <=128 VGPR -> 16 waves/CU (2x r20's 8).
// Wave owns full rows -> alpha epilogue = direct per-head 8-term dots
// (identical order -> al1s bits unchanged; h1b bits unchanged).

#define NSLOPE 0.2f

using bf16x8 = __attribute__((ext_vector_type(8))) short;
using f32x4  = __attribute__((ext_vector_type(4))) float;
using u16x8  = __attribute__((ext_vector_type(8))) unsigned short;
using u16x4  = __attribute__((ext_vector_type(4))) unsigned short;

__device__ __forceinline__ unsigned short bf16_rne(float f) {
    unsigned u = __float_as_uint(f);
    return (unsigned short)((u + 0x7FFFu + ((u >> 16) & 1u)) >> 16);
}
__device__ __forceinline__ float bf16_to_f(unsigned short h) {
    return __uint_as_float(((unsigned)h) << 16);
}

// ----- merged prep: x->Xhi | W1->W1hi (transposed) | W2->W2hi | zero cnt ----
__global__ __launch_bounds__(256) void k_prep_all(const float* __restrict__ x,
                                                  const float* __restrict__ W1,
                                                  const float* __restrict__ W2,
                                                  unsigned short* __restrict__ Xhi,
                                                  unsigned short* __restrict__ W1hi,
                                                  unsigned short* __restrict__ W2hi,
                                                  int* __restrict__ cnt,
                                                  int BX, int total4, int N) {
    int b = blockIdx.x, t = threadIdx.x;
    if (b < BX) {  // x -> bf16 (hi only): 4 floats / thread
        int id = b * 256 + t;
        if (id >= total4) return;
        float4 v = *(const float4*)&x[(size_t)id * 4];
        unsigned short hi[4];
        hi[0] = bf16_rne(v.x); hi[1] = bf16_rne(v.y);
        hi[2] = bf16_rne(v.z); hi[3] = bf16_rne(v.w);
        *(u16x4*)&Xhi[(size_t)id * 4] = *(u16x4*)hi;
    } else if (b < BX + 64) {  // transpose W1 [256,256] -> [n][k], bf16
        int id = (b - BX) * 256 + t;
        int n = id >> 6, kg = id & 63;
        unsigned short hi[4];
#pragma unroll
        for (int c = 0; c < 4; ++c) {
            float w = W1[(kg * 4 + c) * 256 + n];
            hi[c] = bf16_rne(w);
        }
        *(u16x4*)&W1hi[n * 256 + kg * 4] = *(u16x4*)hi;
    } else if (b < BX + 128) {  // transpose W2 [256,64] -> [n][k], bf16
        int id = (b - BX - 64) * 256 + t;
        int n = id >> 8, k = id & 255;
        W2hi[n * 256 + k] = bf16_rne(W2[k * 64 + n]);
    } else {  // zero cnt
        int i = (b - BX - 128) * 256 + t;
        if (i < N) cnt[i] = 0;
    }
}

// -- GEMM1 (+fused fill): 64x256 head-merged tile; wave owns 16 full rows ----
#define G1S 40  // LDS row stride in ushort (32 k + 8 pad)
__global__ __launch_bounds__(256, 4) void k_gemm1(const unsigned short* __restrict__ Xhi,
                                                  const unsigned short* __restrict__ Whi,
                                                  const float* __restrict__ a1s,
                                                  const float* __restrict__ a1d,
                                                  unsigned short* __restrict__ h1b,
                                                  float* __restrict__ as_,
                                                  float* __restrict__ ad_, int M,
                                                  const int* __restrict__ esrc,
                                                  const int* __restrict__ edst,
                                                  int* __restrict__ cnt,
                                                  int* __restrict__ bucket,
                                                  int E, int NG) {
    __shared__ unsigned short sAh[64 * G1S];
    __shared__ unsigned short sBh[256 * G1S];
    int t = threadIdx.x;
    if (blockIdx.x >= NG) {  // trailing blocks: one-shot bucket fill
        int i = (blockIdx.x - NG) * 256 + t;
        if (i < E) {
            int s = esrc[i], d = edst[i];
            int p = atomicAdd(&cnt[d], 1);
            if (p < 63) bucket[(size_t)d * 64 + p] = s;
        }
        return;
    }
    int lane = t & 63, wave = t >> 6;
    int q = lane >> 4, m = lane & 15;
    int row0 = blockIdx.x * 64;
    int rbase = wave * 16;
    f32x4 acc[16];
#pragma unroll
    for (int j = 0; j < 16; ++j) acc[j] = (f32x4){0.f, 0.f, 0.f, 0.f};

    for (int kc = 0; kc < 256; kc += 32) {
        // stage A: 64 rows x 32 k = 256 u16x8 slots, 1 per thread
        {
            int r = t >> 2, kg = t & 3;
            int row = row0 + r;
            u16x8 vh = {0, 0, 0, 0, 0, 0, 0, 0};
            if (row < M) vh = *(const u16x8*)&Xhi[(size_t)row * 256 + kc + kg * 8];
            *(u16x8*)&sAh[r * G1S + kg * 8] = vh;
        }
        // stage B: 256 cols x 32 k, pre-transposed W [n][k], 1024 slots
#pragma unroll
        for (int i2 = 0; i2 < 4; ++i2) {
            int slot = t + i2 * 256;
            int n = slot >> 2, kg = slot & 3;
            *(u16x8*)&sBh[n * G1S + kg * 8] =
                *(const u16x8*)&Whi[(size_t)n * 256 + kc + kg * 8];
        }
        __syncthreads();
        bf16x8 ah = *(bf16x8*)&sAh[(rbase + m) * G1S + q * 8];
#pragma unroll
        for (int j = 0; j < 16; ++j) {
            bf16x8 bh = *(bf16x8*)&sBh[(j * 16 + m) * G1S + q * 8];
            acc[j] = __builtin_amdgcn_mfma_f32_16x16x32_bf16(ah, bh, acc[j], 0, 0, 0);
        }
        __syncthreads();
    }
    float sv[16], dv[16];
#pragma unroll
    for (int j = 0; j < 16; ++j) {
        sv[j] = a1s[j * 16 + m];
        dv[j] = a1d[j * 16 + m];
    }
#pragma unroll
    for (int r = 0; r < 4; ++r) {
        int row = row0 + rbase + q * 4 + r;
        float ps0 = 0.f, pd0 = 0.f, ps1 = 0.f, pd1 = 0.f;
#pragma unroll
        for (int j = 0; j < 8; ++j) {
            ps0 += acc[j][r] * sv[j];
            pd0 += acc[j][r] * dv[j];
            ps1 += acc[8 + j][r] * sv[8 + j];
            pd1 += acc[8 + j][r] * dv[8 + j];
        }
#pragma unroll
        for (int mask = 1; mask < 16; mask <<= 1) {
            ps0 += __shfl_xor(ps0, mask, 64);
            pd0 += __shfl_xor(pd0, mask, 64);
            ps1 += __shfl_xor(ps1, mask, 64);
            pd1 += __shfl_xor(pd1, mask, 64);
        }
        if (row < M) {
#pragma unroll
            for (int j = 0; j < 16; ++j)
                h1b[(size_t)row * 256 + j * 16 + m] = bf16_rne(acc[j][r]);
            if (m == 0) {
                as_[row * 2 + 0] = ps0;
                as_[row * 2 + 1] = ps1;
                ad_[row * 2 + 0] = pd0;
                ad_[row * 2 + 1] = pd1;
            }
        }
    }
}

// ------- layer-1 aggregate: bucket-based, half-wave/edge, 4/2/1 ladder ------
__global__ __launch_bounds__(256) void k_agg1(const unsigned short* __restrict__ h1b,
                                              const float* __restrict__ as,
                                              const float* __restrict__ ad,
                                              const int* __restrict__ cnt,
                                              const int* __restrict__ bucket,
                                              const float* __restrict__ b1,
                                              unsigned short* __restrict__ helu_b, int N) {
    int wid = (blockIdx.x * blockDim.x + threadIdx.x) >> 6;
    int lane = threadIdx.x & 63;
    if (wid >= N) return;
    int c = min(cnt[wid], 63);
    int cntTot = c + 1;   // + self-loop at lane c
    float ad0 = ad[wid * 2], ad1 = ad[wid * 2 + 1];
    int half = lane >> 5, hl = lane & 31;
    int headL = hl >> 4;
    float acc[8];
#pragma unroll
    for (int cc = 0; cc < 8; ++cc) acc[cc] = 0.f;
    float sumw = 0.f;

    int s = (lane < c) ? bucket[(size_t)wid * 64 + lane] : wid;
    float w0 = 0.f, w1 = 0.f;
    if (lane <= c) {
        float2 av = *(const float2*)&as[s * 2];
        float l0 = av.x + ad0; l0 = l0 >= 0.f ? l0 : NSLOPE * l0;
        float l1 = av.y + ad1; l1 = l1 >= 0.f ? l1 : NSLOPE * l1;
        w0 = __expf(l0); w1 = __expf(l1);
    }
    int pairs = (cntTot + 1) >> 1;
    int jj = 0;
    for (; jj + 4 <= pairs; jj += 4) {
        int e0 = 2 * jj + half, e1 = e0 + 2, e2 = e0 + 4, e3 = e0 + 6;
        int sa = __shfl(s, e0, 64), sb = __shfl(s, e1, 64);
        int sc = __shfl(s, e2, 64), se = __shfl(s, e3, 64);
        float wa0 = __shfl(w0, e0, 64), wa1 = __shfl(w1, e0, 64);
        float wb0 = __shfl(w0, e1, 64), wb1 = __shfl(w1, e1, 64);
        float wc0 = __shfl(w0, e2, 64), wc1 = __shfl(w1, e2, 64);
        float wd0 = __shfl(w0, e3, 64), wd1 = __shfl(w1, e3, 64);
        u16x8 hva = *(const u16x8*)&h1b[(size_t)sa * 256 + hl * 8];
        u16x8 hvb = *(const u16x8*)&h1b[(size_t)sb * 256 + hl * 8];
        u16x8 hvc = *(const u16x8*)&h1b[(size_t)sc * 256 + hl * 8];
        u16x8 hvd = *(const u16x8*)&h1b[(size_t)se * 256 + hl * 8];
        float wa = headL ? wa1 : wa0;
        float wb = headL ? wb1 : wb0;
        float wc = headL ? wc1 : wc0;
        float wd = headL ? wd1 : wd0;
        sumw += (wa + wb) + (wc + wd);
#pragma unroll
        for (int cc = 0; cc < 8; ++cc)
            acc[cc] += (wa * bf16_to_f(hva[cc]) + wb * bf16_to_f(hvb[cc]))
                     + (wc * bf16_to_f(hvc[cc]) + wd * bf16_to_f(hvd[cc]));
    }
    for (; jj + 2 <= pairs; jj += 2) {
        int e0 = 2 * jj + half, e1 = e0 + 2;
        int sa = __shfl(s, e0, 64), sb = __shfl(s, e1, 64);
        float wa0 = __shfl(w0, e0, 64), wa1 = __shfl(w1, e0, 64);
        float wb0 = __shfl(w0, e1, 64), wb1 = __shfl(w1, e1, 64);
        u16x8 hva = *(const u16x8*)&h1b[(size_t)sa * 256 + hl * 8];
        u16x8 hvb = *(const u16x8*)&h1b[(size_t)sb * 256 + hl * 8];
        float wa = headL ? wa1 : wa0;
        float wb = headL ? wb1 : wb0;
        sumw += wa + wb;
#pragma unroll
        for (int cc = 0; cc < 8; ++cc)
            acc[cc] += wa * bf16_to_f(hva[cc]) + wb * bf16_to_f(hvb[cc]);
    }
    for (; jj < pairs; ++jj) {
        int e0 = 2 * jj + half;
        int sa = __shfl(s, e0, 64);
        float wa0 = __shfl(w0, e0, 64), wa1 = __shfl(w1, e0, 64);
        u16x8 hva = *(const u16x8*)&h1b[(size_t)sa * 256 + hl * 8];
        float wa = headL ? wa1 : wa0;
        sumw += wa;
#pragma unroll
        for (int cc = 0; cc < 8; ++cc) acc[cc] += wa * bf16_to_f(hva[cc]);
    }
#pragma unroll
    for (int cc = 0; cc < 8; ++cc) acc[cc] += __shfl_xor(acc[cc], 32, 64);
    sumw += __shfl_xor(sumw, 32, 64);
    float inv = 1.0f / sumw;
    int ch = hl * 8 + half * 4;
    float4 bv = *(const float4*)&b1[ch];
    float bb[4] = {bv.x, bv.y, bv.z, bv.w};
    unsigned short o[4];
#pragma unroll
    for (int cc = 0; cc < 4; ++cc) {
        float v = acc[half * 4 + cc] * inv + bb[cc];
        v = v > 0.f ? v : expm1f(v);
        o[cc] = bf16_rne(v);
    }
    *(u16x4*)&helu_b[(size_t)wid * 256 + ch] = *(u16x4*)o;
}

// ---------------- GEMM2: 1-term bf16-A x bf16-B MFMA, alpha2 fused ----------
__global__ __launch_bounds__(256) void k_gemm2(const unsigned short* __restrict__ hb,
                                               const unsigned short* __restrict__ Whi,
                                               const float* __restrict__ a2s,
                                               const float* __restrict__ a2d,
                                               unsigned short* __restrict__ h2b,
                                               float* __restrict__ as_,
                                               float* __restrict__ ad_, int M) {
    __shared__ unsigned short sA[128 * G1S];
    __shared__ unsigned short sBh[64 * G1S];
    int t = threadIdx.x;
    int lane = t & 63, wave = t >> 6;
    int q = lane >> 4, m = lane & 15;
    int row0 = blockIdx.x * 128;
    int rbase = wave * 32;
    f32x4 acc[2][4];
#pragma unroll
    for (int i = 0; i < 2; ++i)
#pragma unroll
        for (int j = 0; j < 4; ++j) acc[i][j] = (f32x4){0.f, 0.f, 0.f, 0.f};

    for (int kc = 0; kc < 256; kc += 32) {
#pragma unroll
        for (int i = 0; i < 2; ++i) {
            int slot = t + i * 256;
            int r = slot >> 2, kg = slot & 3;
            int row = row0 + r;
            u16x8 v = {0, 0, 0, 0, 0, 0, 0, 0};
            if (row < M) v = *(const u16x8*)&hb[(size_t)row * 256 + kc + kg * 8];
            *(u16x8*)&sA[r * G1S + kg * 8] = v;
        }
        {
            int n = t >> 2, kg = t & 3;
            *(u16x8*)&sBh[n * G1S + kg * 8] =
                *(const u16x8*)&Whi[(size_t)n * 256 + kc + kg * 8];
        }
        __syncthreads();
        bf16x8 a[2], bh[4];
#pragma unroll
        for (int i = 0; i < 2; ++i)
            a[i] = *(bf16x8*)&sA[(rbase + i * 16 + m) * G1S + q * 8];
#pragma unroll
        for (int j = 0; j < 4; ++j)
            bh[j] = *(bf16x8*)&sBh[(j * 16 + m) * G1S + q * 8];
#pragma unroll
        for (int i = 0; i < 2; ++i)
#pragma unroll
            for (int j = 0; j < 4; ++j)
                acc[i][j] = __builtin_amdgcn_mfma_f32_16x16x32_bf16(a[i], bh[j], acc[i][j], 0, 0, 0);
        __syncthreads();
    }
    float sv[4], dv[4];
#pragma unroll
    for (int j = 0; j < 4; ++j) {
        sv[j] = a2s[j * 16 + m];
        dv[j] = a2d[j * 16 + m];
    }
#pragma unroll
    for (int i = 0; i < 2; ++i) {
#pragma unroll
        for (int r = 0; r < 4; ++r) {
            int row = row0 + rbase + i * 16 + q * 4 + r;
            float ps = acc[i][0][r] * sv[0] + acc[i][1][r] * sv[1]
                     + acc[i][2][r] * sv[2] + acc[i][3][r] * sv[3];
            float pd = acc[i][0][r] * dv[0] + acc[i][1][r] * dv[1]
                     + acc[i][2][r] * dv[2] + acc[i][3][r] * dv[3];
#pragma unroll
            for (int mask = 1; mask < 16; mask <<= 1) {
                ps += __shfl_xor(ps, mask, 64);
                pd += __shfl_xor(pd, mask, 64);
            }
            if (row < M) {
#pragma unroll
                for (int j = 0; j < 4; ++j)
                    h2b[(size_t)row * 64 + j * 16 + m] = bf16_rne(acc[i][j][r]);
                if (m == 0) { as_[row] = ps; ad_[row] = pd; }
            }
        }
    }
}

// ------- layer-2 aggregate: bucket-based, quarter-wave/edge, 4/2/1 ladder ---
__global__ __launch_bounds__(256) void k_agg2(const unsigned short* __restrict__ h2b,
                                              const float* __restrict__ as,
                                              const float* __restrict__ ad,
                                              const int* __restrict__ cnt,
                                              const int* __restrict__ bucket,
                                              const float* __restrict__ b2,
                                              float* __restrict__ out, int N) {
    int wid = (blockIdx.x * blockDim.x + threadIdx.x) >> 6;
    int lane = threadIdx.x & 63;
    if (wid >= N) return;
    int c = min(cnt[wid], 63);
    int cntTot = c + 1;
    float adw = ad[wid];
    int g = lane >> 4, gl = lane & 15;
    float acc[4];
#pragma unroll
    for (int cc = 0; cc < 4; ++cc) acc[cc] = 0.f;
    float sumw = 0.f;

    int s = (lane < c) ? bucket[(size_t)wid * 64 + lane] : wid;
    float w = 0.f;
    if (lane <= c) {
        float l = as[s] + adw;
        l = l >= 0.f ? l : NSLOPE * l;
        w = __expf(l);
    }
    int quads = (cntTot + 3) >> 2;
    int jj = 0;
    for (; jj + 4 <= quads; jj += 4) {
        int e0 = 4 * jj + g, e1 = e0 + 4, e2 = e0 + 8, e3 = e0 + 12;
        int sa = __shfl(s, e0, 64), sb = __shfl(s, e1, 64);
        int sc = __shfl(s, e2, 64), se = __shfl(s, e3, 64);
        float wa = __shfl(w, e0, 64), wb = __shfl(w, e1, 64);
        float wc = __shfl(w, e2, 64), wd = __shfl(w, e3, 64);
        u16x4 hva = *(const u16x4*)&h2b[(size_t)sa * 64 + gl * 4];
        u16x4 hvb = *(const u16x4*)&h2b[(size_t)sb * 64 + gl * 4];
        u16x4 hvc = *(const u16x4*)&h2b[(size_t)sc * 64 + gl * 4];
        u16x4 hvd = *(const u16x4*)&h2b[(size_t)se * 64 + gl * 4];
        sumw += (wa + wb) + (wc + wd);
        acc[0] += (wa * bf16_to_f(hva.x) + wb * bf16_to_f(hvb.x))
                + (wc * bf16_to_f(hvc.x) + wd * bf16_to_f(hvd.x));
        acc[1] += (wa * bf16_to_f(hva.y) + wb * bf16_to_f(hvb.y))
                + (wc * bf16_to_f(hvc.y) + wd * bf16_to_f(hvd.y));
        acc[2] += (wa * bf16_to_f(hva.z) + wb * bf16_to_f(hvb.z))
                + (wc * bf16_to_f(hvc.z) + wd * bf16_to_f(hvd.z));
        acc[3] += (wa * bf16_to_f(hva.w) + wb * bf16_to_f(hvb.w))
                + (wc * bf16_to_f(hvc.w) + wd * bf16_to_f(hvd.w));
    }
    for (; jj + 2 <= quads; jj += 2) {
        int e0 = 4 * jj + g, e1 = e0 + 4;
        int sa = __shfl(s, e0, 64), sb = __shfl(s, e1, 64);
        float wa = __shfl(w, e0, 64), wb = __shfl(w, e1, 64);
        u16x4 hva = *(const u16x4*)&h2b[(size_t)sa * 64 + gl * 4];
        u16x4 hvb = *(const u16x4*)&h2b[(size_t)sb * 64 + gl * 4];
        sumw += wa + wb;
        acc[0] += wa * bf16_to_f(hva.x) + wb * bf16_to_f(hvb.x);
        acc[1] += wa * bf16_to_f(hva.y) + wb * bf16_to_f(hvb.y);
        acc[2] += wa * bf16_to_f(hva.z) + wb * bf16_to_f(hvb.z);
        acc[3] += wa * bf16_to_f(hva.w) + wb * bf16_to_f(hvb.w);
    }
    for (; jj < quads; ++jj) {
        int e0 = 4 * jj + g;
        int sa = __shfl(s, e0, 64);
        float wa = __shfl(w, e0, 64);
        u16x4 hva = *(const u16x4*)&h2b[(size_t)sa * 64 + gl * 4];
        sumw += wa;
        acc[0] += wa * bf16_to_f(hva.x);
        acc[1] += wa * bf16_to_f(hva.y);
        acc[2] += wa * bf16_to_f(hva.z);
        acc[3] += wa * bf16_to_f(hva.w);
    }
#pragma unroll
    for (int cc = 0; cc < 4; ++cc) {
        acc[cc] += __shfl_xor(acc[cc], 16, 64);
        acc[cc] += __shfl_xor(acc[cc], 32, 64);
    }
    sumw += __shfl_xor(sumw, 16, 64);
    sumw += __shfl_xor(sumw, 32, 64);
    if (g == 0) {
        float inv = 1.0f / sumw;
        float4 bv = *(const float4*)&b2[gl * 4];
        float4 o;
        o.x = acc[0] * inv + bv.x;
        o.y = acc[1] * inv + bv.y;
        o.z = acc[2] * inv + bv.z;
        o.w = acc[3] * inv + bv.w;
        *(float4*)&out[(size_t)wid * 64 + gl * 4] = o;
    }
}

// ---------------- launch ----------------
extern "C" void kernel_launch(void* const* d_in, const int* in_sizes, int n_in,
                              void* d_out, int out_size, void* d_ws, size_t ws_size,
                              hipStream_t stream) {
    if (n_in < 10) return;
    const float* x   = (const float*)d_in[0];
    const int*   ei  = (const int*)d_in[1];
    const float* W1  = (const float*)d_in[2];
    const float* a1s = (const float*)d_in[3];
    const float* a1d = (const float*)d_in[4];
    const float* b1  = (const float*)d_in[5];
    const float* W2  = (const float*)d_in[6];
    const float* a2s = (const float*)d_in[7];
    const float* a2d = (const float*)d_in[8];
    const float* b2  = (const float*)d_in[9];
    float* out = (float*)d_out;

    const int N = in_sizes[0] / 256;
    const int E = in_sizes[1] / 2;
    const int* esrc = ei;
    const int* edst = ei + E;

    char* ws = (char*)d_ws;
    size_t o = 0;
    auto alloc = [&](size_t bytes) -> void* {
        void* p = ws + o;
        o = (o + bytes + 255) & ~(size_t)255;
        return p;
    };
    // Xhi (dead after gemm1) aliased with helu_b (written by agg1)
    size_t szX = (size_t)N * 256 * 2;
    char* regionA = (char*)alloc(szX);
    unsigned short* Xhi    = (unsigned short*)regionA;
    unsigned short* helu_b = (unsigned short*)regionA;

    unsigned short* h1b  = (unsigned short*)alloc((size_t)N * 256 * 2);
    unsigned short* W1hi = (unsigned short*)alloc(256 * 256 * 2);
    unsigned short* W2hi = (unsigned short*)alloc(64 * 256 * 2);
    unsigned short* h2b  = (unsigned short*)alloc((size_t)N * 64 * 2);
    float* al1s = (float*)alloc((size_t)N * 2 * 4);
    float* al1d = (float*)alloc((size_t)N * 2 * 4);
    float* al2s = (float*)alloc((size_t)N * 4);
    float* al2d = (float*)alloc((size_t)N * 4);
    int* cnt    = (int*)alloc((size_t)N * 4);
    int* bucket = (int*)alloc((size_t)N * 64 * 4);
    if (o > ws_size) return;

    const int total4 = N * 64;
    const int BX = (total4 + 255) / 256;
    const int BZ = (N + 255) / 256;
    const int NG = (N + 63) / 64;        // gemm blocks (64 rows each)
    const int FB = (E + 255) / 256;      // one-shot fill blocks

    k_prep_all<<<BX + 128 + BZ, 256, 0, stream>>>(x, W1, W2, Xhi,
                                                  W1hi, W2hi, cnt,
                                                  BX, total4, N);
    k_gemm1<<<NG + FB, 256, 0, stream>>>(Xhi, W1hi, a1s, a1d, h1b, al1s, al1d, N,
                                         esrc, edst, cnt, bucket, E, NG);
    k_agg1<<<(N + 3) / 4, 256, 0, stream>>>(h1b, al1s, al1d, cnt, bucket, b1, helu_b, N);

    // layer 2
    k_gemm2<<<(N + 127) / 128, 256, 0, stream>>>(helu_b, W2hi, a2s, a2d,
                                                 h2b, al2s, al2d, N);
    k_agg2<<<(N + 3) / 4, 256, 0, stream>>>(h2b, al2s, al2d, cnt, bucket, b2, out, N);
}